// Round 1
// baseline (321.867 us; speedup 1.0000x reference)
//
#include <hip/hip_runtime.h>
#include <math.h>

// Problem constants (from reference)
#define NCH 129
#define BS 8
#define TLEN 64000
#define LFRM 256          // frame stride == chunk length
#define NFRM 250          // number of frames / chunks (ceil(63999/256))
#define NSEQ (NCH * BS)   // 1032 independent (channel,batch) sequences

// Warm-up: beta-state only needs the last WARM_BETA samples of prev chunk
// (beta^160 * max_state(8.5) ~ 1.7e-8 absolute error)
#define WARM_SKIP 96      // IIR-only steps at head of warm-up chunk

struct Coef { float b0, b1, b2, b3, b4, a1, a2, a3, a4; };

__device__ __forceinline__ Coef load_coef(const float* __restrict__ B,
                                          const float* __restrict__ A, int c) {
    Coef q;
    q.b0 = B[c * 5 + 0]; q.b1 = B[c * 5 + 1]; q.b2 = B[c * 5 + 2];
    q.b3 = B[c * 5 + 3]; q.b4 = B[c * 5 + 4];
    q.a1 = A[c * 5 + 1]; q.a2 = A[c * 5 + 2];
    q.a3 = A[c * 5 + 3]; q.a4 = A[c * 5 + 4];
    return q;
}

// Direct-form II transposed, order 4. Returns y, updates state in place.
__device__ __forceinline__ float iir_step(const Coef& q, float x,
                                          float& z0, float& z1, float& z2, float& z3) {
    float y = fmaf(q.b0, x, z0);
    z0 = fmaf(-q.a1, y, fmaf(q.b1, x, z1));
    z1 = fmaf(-q.a2, y, fmaf(q.b2, x, z2));
    z2 = fmaf(-q.a3, y, fmaf(q.b3, x, z3));
    z3 = fmaf(-q.a4, y, q.b4 * x);
    return y;
}

__device__ __forceinline__ float sigmoidf(float x) {
    return 1.0f / (1.0f + __expf(-x));
}

// ---------------------------------------------------------------------------
// Kernel A: per (c, b, chunk) run order-4 IIR with zero initial state over the
// chunk; store final 4-state d (the forced response). One block per (b,chunk),
// threads over channels, input chunk staged in LDS (broadcast reads).
// ---------------------------------------------------------------------------
__global__ __launch_bounds__(192) void kA_forced_state(
        const float* __restrict__ wav, const float* __restrict__ B,
        const float* __restrict__ A, float* __restrict__ zs) {
    __shared__ float xs[LFRM];
    int blk = blockIdx.x;            // b * NFRM + k
    int b = blk / NFRM;
    int k = blk - b * NFRM;
    const float* xg = wav + (size_t)b * TLEN + (size_t)k * LFRM;
    for (int i = threadIdx.x; i < LFRM; i += 192) xs[i] = xg[i];
    __syncthreads();
    int c = threadIdx.x;
    if (c >= NCH) return;
    Coef q = load_coef(B, A, c);
    float z0 = 0.f, z1 = 0.f, z2 = 0.f, z3 = 0.f;
    #pragma unroll 8
    for (int j = 0; j < LFRM; ++j) {
        (void)iir_step(q, xs[j], z0, z1, z2, z3);
    }
    *(float4*)(zs + ((size_t)(c * BS + b) * NFRM + k) * 4) =
        make_float4(z0, z1, z2, z3);
}

// ---------------------------------------------------------------------------
// Kernel B: per (c, b) sequence — compute M^256 (repeated squaring of the 4x4
// companion matrix) and scan chunk states in place:
//   z_in[k] = M^L * z_in[k-1] + d[k-1],  z_in[0] = 0.
// ---------------------------------------------------------------------------
__global__ __launch_bounds__(64) void kB_state_scan(
        const float* __restrict__ A, float* __restrict__ zs) {
    int id = blockIdx.x * 64 + threadIdx.x;   // c * BS + b
    if (id >= NSEQ) return;
    int c = id / BS;
    float a1 = A[c * 5 + 1], a2 = A[c * 5 + 2], a3 = A[c * 5 + 3], a4 = A[c * 5 + 4];
    float M[4][4] = {{-a1, 1.f, 0.f, 0.f},
                     {-a2, 0.f, 1.f, 0.f},
                     {-a3, 0.f, 0.f, 1.f},
                     {-a4, 0.f, 0.f, 0.f}};
    for (int s = 0; s < 8; ++s) {        // M^(2^8) = M^256
        float R[4][4];
        for (int i = 0; i < 4; ++i)
            for (int j = 0; j < 4; ++j) {
                float acc = 0.f;
                for (int t = 0; t < 4; ++t) acc = fmaf(M[i][t], M[t][j], acc);
                R[i][j] = acc;
            }
        for (int i = 0; i < 4; ++i)
            for (int j = 0; j < 4; ++j) M[i][j] = R[i][j];
    }
    float4* base = (float4*)(zs + (size_t)id * NFRM * 4);
    float s0 = 0.f, s1 = 0.f, s2 = 0.f, s3 = 0.f;
    for (int k = 0; k < NFRM; ++k) {
        float4 d = base[k];
        base[k] = make_float4(s0, s1, s2, s3);   // overwrite with z_in[k]
        float n0 = fmaf(M[0][0], s0, fmaf(M[0][1], s1, fmaf(M[0][2], s2, fmaf(M[0][3], s3, d.x))));
        float n1 = fmaf(M[1][0], s0, fmaf(M[1][1], s1, fmaf(M[1][2], s2, fmaf(M[1][3], s3, d.y))));
        float n2 = fmaf(M[2][0], s0, fmaf(M[2][1], s1, fmaf(M[2][2], s2, fmaf(M[2][3], s3, d.z))));
        float n3 = fmaf(M[3][0], s0, fmaf(M[3][1], s1, fmaf(M[3][2], s2, fmaf(M[3][3], s3, d.w))));
        s0 = n0; s1 = n1; s2 = n2; s3 = n3;
    }
}

// ---------------------------------------------------------------------------
// Kernel C (dominant): per (output channel c in 1..128, b, chunk k):
//  - start both channel chains (c and c-1) from exact z_in[k-1]
//  - warm-up over chunk k-1 (IIR always; sigmoid+beta only last 160 steps —
//    beta^256=e^-32 makes the incoming beta state at chunk k-1 negligible)
//  - main pass over chunk k: y4 = relu(y2s[c]-y2s[c-1]); accumulate
//    G = sum alpha^(L-1-i) y4[i] and record y4[t0].
// Channel 0's y4 is identically 0 (y2_prev[0]=y2[0]) -> handled in kernel D.
// ---------------------------------------------------------------------------
__global__ __launch_bounds__(128) void kC_main(
        const float* __restrict__ wav, const float* __restrict__ B,
        const float* __restrict__ A, const float* __restrict__ zs,
        float* __restrict__ G, float* __restrict__ y4f,
        float beta, float alpha) {
    __shared__ float xs[2 * LFRM];
    int blk = blockIdx.x;            // b * NFRM + k
    int b = blk / NFRM;
    int k = blk - b * NFRM;
    int kload = (k > 0) ? (k - 1) : 0;
    int nload = (k > 0) ? 2 * LFRM : LFRM;
    const float* xg = wav + (size_t)b * TLEN + (size_t)kload * LFRM;
    for (int i = threadIdx.x; i < nload; i += 128) xs[i] = xg[i];
    __syncthreads();

    int c = threadIdx.x + 1;         // 1..128, all valid (NCH=129)
    Coef qa = load_coef(B, A, c);
    Coef qb = load_coef(B, A, c - 1);
    float za0 = 0.f, za1 = 0.f, za2 = 0.f, za3 = 0.f;
    float zb0 = 0.f, zb1 = 0.f, zb2 = 0.f, zb3 = 0.f;
    float ua = 0.f, ub = 0.f;        // beta states
    int off = 0;
    if (k > 0) {
        float4 va = *(const float4*)(zs + ((size_t)(c * BS + b) * NFRM + (k - 1)) * 4);
        float4 vb = *(const float4*)(zs + ((size_t)((c - 1) * BS + b) * NFRM + (k - 1)) * 4);
        za0 = va.x; za1 = va.y; za2 = va.z; za3 = va.w;
        zb0 = vb.x; zb1 = vb.y; zb2 = vb.z; zb3 = vb.w;
        // head of warm-up chunk: IIR state evolution only
        #pragma unroll 4
        for (int j = 0; j < WARM_SKIP; ++j) {
            float x = xs[j];
            (void)iir_step(qa, x, za0, za1, za2, za3);
            (void)iir_step(qb, x, zb0, zb1, zb2, zb3);
        }
        // tail of warm-up chunk: IIR + sigmoid + beta accumulation
        #pragma unroll 4
        for (int j = WARM_SKIP; j < LFRM; ++j) {
            float x = xs[j];
            float ya = iir_step(qa, x, za0, za1, za2, za3);
            float yb = iir_step(qb, x, zb0, zb1, zb2, zb3);
            ua = fmaf(beta, ua, sigmoidf(ya));
            ub = fmaf(beta, ub, sigmoidf(yb));
        }
        off = LFRM;
    }
    float g = 0.f, yfirst = 0.f;
    #pragma unroll 4
    for (int j = 0; j < LFRM; ++j) {
        float x = xs[off + j];
        float ya = iir_step(qa, x, za0, za1, za2, za3);
        float yb = iir_step(qb, x, zb0, zb1, zb2, zb3);
        ua = fmaf(beta, ua, sigmoidf(ya));
        ub = fmaf(beta, ub, sigmoidf(yb));
        float y4 = fmaxf(ua - ub, 0.0f);
        if (j == 0) yfirst = y4;
        g = fmaf(alpha, g, y4);
    }
    size_t idx = (size_t)(c * BS + b) * NFRM + k;
    G[idx] = g;
    y4f[idx] = yfirst;
}

// ---------------------------------------------------------------------------
// Kernel D: per (c, b) exclusive alpha-scan over chunks; frame k output is
//   y5[256k] = alpha * s_in[k] + y4[256k],  s_in[k+1] = alpha^L s_in[k] + G[k].
// Output layout (BS, NCH, NFRM).
// ---------------------------------------------------------------------------
__global__ __launch_bounds__(64) void kD_alpha_scan(
        const float* __restrict__ G, const float* __restrict__ y4f,
        float* __restrict__ out, float alpha, float alphaL) {
    int id = blockIdx.x * 64 + threadIdx.x;   // c * BS + b
    if (id >= NSEQ) return;
    int c = id / BS;
    int b = id - c * BS;
    float* o = out + ((size_t)b * NCH + c) * NFRM;
    if (c == 0) {
        for (int k = 0; k < NFRM; ++k) o[k] = 0.0f;
        return;
    }
    const float* g = G + (size_t)id * NFRM;
    const float* yf = y4f + (size_t)id * NFRM;
    float s = 0.f;
    for (int k = 0; k < NFRM; ++k) {
        o[k] = fmaf(alpha, s, yf[k]);
        s = fmaf(alphaL, s, g[k]);
    }
}

// ---------------------------------------------------------------------------
extern "C" void kernel_launch(void* const* d_in, const int* in_sizes, int n_in,
                              void* d_out, int out_size, void* d_ws, size_t ws_size,
                              hipStream_t stream) {
    const float* wav = (const float*)d_in[0];   // (BS, TLEN)
    const float* Bc  = (const float*)d_in[1];   // (NCH, 5)
    const float* Ac  = (const float*)d_in[2];   // (NCH, 5)
    float* out = (float*)d_out;                 // (BS, NCH, NFRM)

    // workspace layout: zs (NSEQ*NFRM*4) | G (NSEQ*NFRM) | y4f (NSEQ*NFRM)
    float* zs  = (float*)d_ws;
    float* G   = zs + (size_t)NSEQ * NFRM * 4;
    float* y4f = G + (size_t)NSEQ * NFRM;

    const float alpha  = (float)exp(-1.0 / 128.0);   // TC=8, 2^4
    const float beta   = (float)exp(-1.0 / 8.0);     // HAIR_TC=0.5
    const float alphaL = (float)exp(-256.0 / 128.0); // alpha^LFRM

    kA_forced_state<<<BS * NFRM, 192, 0, stream>>>(wav, Bc, Ac, zs);
    kB_state_scan<<<(NSEQ + 63) / 64, 64, 0, stream>>>(Ac, zs);
    kC_main<<<BS * NFRM, 128, 0, stream>>>(wav, Bc, Ac, zs, G, y4f, beta, alpha);
    kD_alpha_scan<<<(NSEQ + 63) / 64, 64, 0, stream>>>(G, y4f, out, alpha, alphaL);
}